// Round 2
// 714.537 us; speedup vs baseline: 1.3058x; 1.3058x over previous
//
#include <hip/hip_runtime.h>
#include <math.h>

#define B_ 128
#define L_ 512
#define D_ 512
#define E_ 64
#define H_ 512
#define V_ 17

#define LOG2E_F 1.4426950408889634f
#define LN2_F   0.6931471805599453f

__device__ __forceinline__ float fast_tanh(float x) {
  // tanh(x) = 1 - 2/(1+e^{2x}); saturates correctly via exp2 over/underflow
  float e = __builtin_amdgcn_exp2f(x * (2.0f * LOG2E_F));
  return 1.0f - 2.0f * __builtin_amdgcn_rcpf(e + 1.0f);
}

// ---------------- DH precompute: DH[v][h] = sum_e W1[h][D+e] * table[v][e], row 0 zeroed
__global__ void dh_kernel(const float* __restrict__ W1, const float* __restrict__ table,
                          float* __restrict__ DH) {
  int h = threadIdx.x; // 512 threads
  float w[E_];
#pragma unroll
  for (int e = 0; e < E_; ++e) w[e] = W1[h * (D_ + E_) + D_ + e];
  DH[h] = 0.f; // v = 0 (PAD row is zero)
  for (int v = 1; v < V_; ++v) {
    float acc = 0.f;
#pragma unroll
    for (int e = 0; e < E_; ++e) acc += w[e] * table[v * E_ + e];
    DH[v * H_ + h] = acc;
  }
}

// ---------------- split-fp16 3xMFMA GEMM: Z = A * W^T + b1 (unchanged from prev round)
#define GBM 128
#define GBN 128
#define GBK 32
#define PITCH 20          // dwords per row: 16 data + 4 pad
#define SCALE_A 1024.0f
#define SCALE_W 256.0f
#define INV_SCALE (1.0f / (1024.0f * 256.0f))

typedef _Float16 half8 __attribute__((ext_vector_type(8)));
typedef float float4v __attribute__((ext_vector_type(4)));

__device__ __forceinline__ uint4 split4(float4 v, float scale) {
  float a0 = v.x * scale, a1 = v.y * scale, a2 = v.z * scale, a3 = v.w * scale;
  _Float16 h0 = (_Float16)a0, h1 = (_Float16)a1, h2 = (_Float16)a2, h3 = (_Float16)a3;
  _Float16 l0 = (_Float16)(a0 - (float)h0), l1 = (_Float16)(a1 - (float)h1);
  _Float16 l2 = (_Float16)(a2 - (float)h2), l3 = (_Float16)(a3 - (float)h3);
  union { _Float16 h; unsigned short u; } c;
  unsigned int hu0, hu1, hu2, hu3, lu0, lu1, lu2, lu3;
  c.h = h0; hu0 = c.u; c.h = h1; hu1 = c.u; c.h = h2; hu2 = c.u; c.h = h3; hu3 = c.u;
  c.h = l0; lu0 = c.u; c.h = l1; lu1 = c.u; c.h = l2; lu2 = c.u; c.h = l3; lu3 = c.u;
  uint4 r;
  r.x = hu0 | (hu1 << 16);
  r.y = hu2 | (hu3 << 16);
  r.z = lu0 | (lu1 << 16);
  r.w = lu2 | (lu3 << 16);
  return r;
}

__global__ __launch_bounds__(256, 2)
void gemm_kernel(const float* __restrict__ A, const float* __restrict__ W1,
                 const float* __restrict__ b1, float* __restrict__ Z) {
  __shared__ unsigned int Ahi[GBM * PITCH], Alo[GBM * PITCH];
  __shared__ unsigned int Whi[GBN * PITCH], Wlo[GBN * PITCH];

  const int t = threadIdx.x;
  const int ln = t & 63, w = t >> 6;
  const int wm = w & 1, wn = w >> 1;
  const int mBase = blockIdx.x * GBM;
  const int nBase = blockIdx.y * GBN;
  const int lrow = ln & 15, lquad = ln >> 4;

  float4v acc[4][4];
#pragma unroll
  for (int i = 0; i < 4; ++i)
#pragma unroll
    for (int j = 0; j < 4; ++j) acc[i][j] = (float4v){0.f, 0.f, 0.f, 0.f};

  for (int kt = 0; kt < D_; kt += GBK) {
#pragma unroll
    for (int q = 0; q < 4; ++q) {
      const int idx = q * 256 + t;
      const int m = idx >> 3, f = idx & 7;
      const float4 av = *(const float4*)&A[(size_t)(mBase + m) * D_ + kt + 4 * f];
      const uint4 pa = split4(av, SCALE_A);
      *(uint2*)&Ahi[m * PITCH + 2 * f] = make_uint2(pa.x, pa.y);
      *(uint2*)&Alo[m * PITCH + 2 * f] = make_uint2(pa.z, pa.w);
      const float4 wv = *(const float4*)&W1[(size_t)(nBase + m) * (D_ + E_) + kt + 4 * f];
      const uint4 pw = split4(wv, SCALE_W);
      *(uint2*)&Whi[m * PITCH + 2 * f] = make_uint2(pw.x, pw.y);
      *(uint2*)&Wlo[m * PITCH + 2 * f] = make_uint2(pw.z, pw.w);
    }
    __syncthreads();

    half8 ah[4], al[4], bh[4], bl[4];
#pragma unroll
    for (int tm = 0; tm < 4; ++tm) {
      const int off = (wm * 64 + tm * 16 + lrow) * PITCH + 4 * lquad;
      ah[tm] = *(const half8*)&Ahi[off];
      al[tm] = *(const half8*)&Alo[off];
    }
#pragma unroll
    for (int tn = 0; tn < 4; ++tn) {
      const int off = (wn * 64 + tn * 16 + lrow) * PITCH + 4 * lquad;
      bh[tn] = *(const half8*)&Whi[off];
      bl[tn] = *(const half8*)&Wlo[off];
    }
#pragma unroll
    for (int tm = 0; tm < 4; ++tm)
#pragma unroll
      for (int tn = 0; tn < 4; ++tn) {
        acc[tm][tn] = __builtin_amdgcn_mfma_f32_16x16x32_f16(ah[tm], bh[tn], acc[tm][tn], 0, 0, 0);
        acc[tm][tn] = __builtin_amdgcn_mfma_f32_16x16x32_f16(ah[tm], bl[tn], acc[tm][tn], 0, 0, 0);
        acc[tm][tn] = __builtin_amdgcn_mfma_f32_16x16x32_f16(al[tm], bh[tn], acc[tm][tn], 0, 0, 0);
      }
    __syncthreads();
  }

#pragma unroll
  for (int tn = 0; tn < 4; ++tn) {
    const int col = nBase + wn * 64 + tn * 16 + lrow;
    const float bv = b1[col];
#pragma unroll
    for (int tm = 0; tm < 4; ++tm) {
      const int row0 = mBase + wm * 64 + tm * 16 + lquad * 4;
#pragma unroll
      for (int r = 0; r < 4; ++r)
        Z[(size_t)(row0 + r) * H_ + col] = acc[tm][tn][r] * INV_SCALE + bv;
    }
  }
}

// ---------------- lg_kernel: for 16 (b,t) rows, compute ALL 17 prev-pred variants:
//   G[bt][p][v] = sum_h tanh(Z[bt][h] + DH[p][h]) * W2[v][h] + b2[v]
//   next[bt][p] = argmax_v G[bt][p][v]   (first-max tie rule, matches jnp.argmax)
// G is written IN PLACE over Z's 512-float slot:
//   floats p*20..p*20+16 hold the 17 logits for prev-pred p (17 rows x 20 pitch = 340)
//   dwords 352..356 hold the 17 next-bytes (packed).
// Safe: block stages its 16 Z rows to LDS before any G write; no other block
// touches these slots. v in 0..15 via 3-pass split-fp16 MFMA (same error class
// as gemm_kernel); v=16 via fp32 VALU dot (avoids a 94%-wasted second n-tile).
#define LG_ROWS 16
#define ZP 516   // f32 pitch for sZ/sDH: (516*4)%128=16 -> 2-way banks, free
#define WP 260   // dword pitch for packed W2 halves

__global__ __launch_bounds__(256, 1)
void lg_kernel(const float* Zin, const float* __restrict__ DH,
               const float* __restrict__ W2, const float* __restrict__ b2,
               float* G) {               // G aliases Zin (no __restrict__!)
  __shared__ float sZ[LG_ROWS * ZP];          // 33,024 B
  __shared__ float sDH[V_ * ZP];              // 35,088 B
  __shared__ unsigned int sW2hi[16 * WP];     // 16,640 B  (v = 0..15)
  __shared__ unsigned int sW2lo[16 * WP];     // 16,640 B
  __shared__ float sW16[H_];                  //  2,048 B  (v = 16, raw f32)
  __shared__ float sS[4][LG_ROWS][20];        //  5,120 B  per-wave transpose scratch
  __shared__ unsigned char nb[LG_ROWS][32];   //    512 B  next bytes

  const int t = threadIdx.x;
  const int ln = t & 63, w = t >> 6;          // 4 waves
  const int bt0 = blockIdx.x * LG_ROWS;

  // ---- stage Z tile (16 x 512)
#pragma unroll
  for (int i = 0; i < 8; ++i) {
    const int f = t + 256 * i;                    // 0..2047
    const int r = f >> 7, c = (f & 127) * 4;
    *(float4*)&sZ[r * ZP + c] = *(const float4*)&Zin[(size_t)(bt0 + r) * H_ + c];
  }
  // ---- stage DH (17 x 512)
#pragma unroll
  for (int i = 0; i < 9; ++i) {
    const int f = t + 256 * i;
    if (f < (V_ * H_ / 4)) {
      const int r = f >> 7, c = (f & 127) * 4;
      *(float4*)&sDH[r * ZP + c] = *(const float4*)&DH[(size_t)r * H_ + c];
    }
  }
  // ---- stage + split W2 rows 0..15 (scaled x256), row 16 raw
#pragma unroll
  for (int i = 0; i < 8; ++i) {
    const int f = t + 256 * i;                    // 0..2047 = 16 rows x 128 f4
    const int r = f >> 7, c = (f & 127) * 4;
    const float4 wv = *(const float4*)&W2[(size_t)r * H_ + c];
    const uint4 pw = split4(wv, SCALE_W);
    *(uint2*)&sW2hi[r * WP + (c >> 1)] = make_uint2(pw.x, pw.y);
    *(uint2*)&sW2lo[r * WP + (c >> 1)] = make_uint2(pw.z, pw.w);
  }
  if (t < 128) *(float4*)&sW16[t * 4] = *(const float4*)&W2[(size_t)16 * H_ + t * 4];
  __syncthreads();

  const int lrow = ln & 15, lq = ln >> 4;
  const float b2a = b2[lrow];
  const float b2c = b2[16];

  for (int p = w; p < V_; p += 4) {
    float4v acc0 = (float4v){0.f, 0.f, 0.f, 0.f};
    float p16 = 0.f;
    for (int kt = 0; kt < H_; kt += 32) {
      const float* zr = &sZ[lrow * ZP + kt + lq * 8];
      const float* dr = &sDH[p * ZP + kt + lq * 8];
      float a[8];
#pragma unroll
      for (int j = 0; j < 8; ++j) {
        const float x = zr[j] + dr[j];
        const float e = __builtin_amdgcn_exp2f(x * (2.0f * LOG2E_F));
        // a = 1024 * tanh(x), scale folded into the fma
        a[j] = fmaf(-2048.0f, __builtin_amdgcn_rcpf(e + 1.0f), 1024.0f);
      }
      half8 ah, al;
#pragma unroll
      for (int j = 0; j < 8; ++j) {
        const _Float16 h = (_Float16)a[j];
        ah[j] = h;
        al[j] = (_Float16)(a[j] - (float)h);
      }
      const int wo = (kt >> 1) + lq * 4;
      const half8 bh0 = *(const half8*)&sW2hi[lrow * WP + wo];
      const half8 bl0 = *(const half8*)&sW2lo[lrow * WP + wo];
      acc0 = __builtin_amdgcn_mfma_f32_16x16x32_f16(ah, bh0, acc0, 0, 0, 0);
      acc0 = __builtin_amdgcn_mfma_f32_16x16x32_f16(ah, bl0, acc0, 0, 0, 0);
      acc0 = __builtin_amdgcn_mfma_f32_16x16x32_f16(al, bh0, acc0, 0, 0, 0);
      const float* wr = &sW16[kt + lq * 8];       // uniform across lrow: broadcast
#pragma unroll
      for (int j = 0; j < 8; ++j) p16 = fmaf(a[j], wr[j], p16);
    }
    // v16: reduce over the 4 k-quadrant lanes of each row
    p16 += __shfl_xor(p16, 16, 64);
    p16 += __shfl_xor(p16, 32, 64);
    // transpose C quadrant through LDS: C[row=lq*4+r][col=lrow]
#pragma unroll
    for (int r = 0; r < 4; ++r)
      sS[w][lq * 4 + r][lrow] = acc0[r] * INV_SCALE + b2a;
    if (ln < 16) {                                 // lane == row, lq==0
      float va[17];
      const float4 q0 = *(const float4*)&sS[w][ln][0];
      const float4 q1 = *(const float4*)&sS[w][ln][4];
      const float4 q2 = *(const float4*)&sS[w][ln][8];
      const float4 q3 = *(const float4*)&sS[w][ln][12];
      va[0] = q0.x; va[1] = q0.y; va[2] = q0.z; va[3] = q0.w;
      va[4] = q1.x; va[5] = q1.y; va[6] = q1.z; va[7] = q1.w;
      va[8] = q2.x; va[9] = q2.y; va[10] = q2.z; va[11] = q2.w;
      va[12] = q3.x; va[13] = q3.y; va[14] = q3.z; va[15] = q3.w;
      va[16] = p16 * (1.0f / 1024.0f) + b2c;
      float m = va[0]; int am = 0;
#pragma unroll
      for (int i = 1; i < 17; ++i) if (va[i] > m) { m = va[i]; am = i; }
      float* gs = &G[(size_t)(bt0 + ln) * H_ + p * 20];
      *(float4*)&gs[0] = q0; *(float4*)&gs[4] = q1;
      *(float4*)&gs[8] = q2; *(float4*)&gs[12] = q3;
      gs[16] = va[16];
      nb[ln][p] = (unsigned char)am;
    }
  }
  __syncthreads();
  // pack next bytes into dwords 352..356 of each slot
  if (t < 80) {
    const int row = t / 5, d = t % 5;
    ((unsigned int*)&G[(size_t)(bt0 + row) * H_ + 352])[d] =
        *(const unsigned int*)&nb[row][d * 4];
  }
}

// ---------------- chase_kernel: the entire recurrence is now a byte-table walk.
// One wave per batch row; next-table (512 x 17B, pitch 32) prefetched to LDS;
// critical path = 512 dependent ds_read_u8 (~125 cy each).
__global__ __launch_bounds__(64, 1)
void chase_kernel(const float* __restrict__ G, float* __restrict__ out_preds) {
  __shared__ unsigned char nxt[L_ * 32];   // 16 KB
  const int b = blockIdx.x, ln = threadIdx.x;
#pragma unroll
  for (int i = 0; i < 8; ++i) {
    const int tt = ln + 64 * i;
    const unsigned int* src = (const unsigned int*)&G[((size_t)b * L_ + tt) * H_ + 352];
    *(uint4*)&nxt[tt * 32] = *(const uint4*)src;
    *(unsigned int*)&nxt[tt * 32 + 16] = src[4];
  }
  __syncthreads();
  int pred = 0;
  float* op = out_preds + (size_t)b * L_;
  for (int tt = 0; tt < L_; ++tt) {
    pred = nxt[tt * 32 + pred];
    if (ln == 0) op[tt] = (float)pred;
  }
}

// ---------------- epi_kernel: embarrassingly-parallel outputs from G + preds.
__global__ __launch_bounds__(256)
void epi_kernel(const float* __restrict__ G, const float* __restrict__ table,
                const float* __restrict__ preds,
                float* __restrict__ out_logits, float* __restrict__ out_probs,
                float* __restrict__ out_pemb) {
  const int bt = blockIdx.x * 256 + threadIdx.x;
  const int tt = bt & (L_ - 1);
  const int p = (tt == 0) ? 0 : (int)preds[bt - 1];
  const float* g = &G[(size_t)bt * H_ + p * 20];
  float va[17];
  {
    const float4 q0 = *(const float4*)&g[0];
    const float4 q1 = *(const float4*)&g[4];
    const float4 q2 = *(const float4*)&g[8];
    const float4 q3 = *(const float4*)&g[12];
    va[0] = q0.x; va[1] = q0.y; va[2] = q0.z; va[3] = q0.w;
    va[4] = q1.x; va[5] = q1.y; va[6] = q1.z; va[7] = q1.w;
    va[8] = q2.x; va[9] = q2.y; va[10] = q2.z; va[11] = q2.w;
    va[12] = q3.x; va[13] = q3.y; va[14] = q3.z; va[15] = q3.w;
    va[16] = g[16];
  }
  float m = va[0];
#pragma unroll
  for (int i = 1; i < 17; ++i) m = fmaxf(m, va[i]);
  float s = 0.f;
#pragma unroll
  for (int i = 0; i < 17; ++i) s += __builtin_amdgcn_exp2f((va[i] - m) * LOG2E_F);
  const float lse = __builtin_amdgcn_logf(s) * LN2_F;
  float* lo = out_logits + (size_t)bt * V_;
  float* pb = out_probs + (size_t)bt * V_;
#pragma unroll
  for (int i = 0; i < 17; ++i) { lo[i] = va[i]; pb[i] = va[i] - m - lse; }
  const int pr = (int)preds[bt];
  float* pe = out_pemb + (size_t)bt * E_;
  if (pr == 0) {
#pragma unroll
    for (int i = 0; i < 16; ++i) *(float4*)&pe[4 * i] = (float4){0.f, 0.f, 0.f, 0.f};
  } else {
    const float* tr = &table[(size_t)pr * E_];
#pragma unroll
    for (int i = 0; i < 16; ++i) *(float4*)&pe[4 * i] = *(const float4*)&tr[4 * i];
  }
}

extern "C" void kernel_launch(void* const* d_in, const int* in_sizes, int n_in,
                              void* d_out, int out_size, void* d_ws, size_t ws_size,
                              hipStream_t stream) {
  const float* inputs = (const float*)d_in[0];
  const float* table  = (const float*)d_in[1];
  const float* W1     = (const float*)d_in[2];
  const float* b1     = (const float*)d_in[3];
  const float* W2     = (const float*)d_in[4];
  const float* b2     = (const float*)d_in[5];

  float* out = (float*)d_out;
  float* out_logits = out;                                  // [B,L,V]
  float* out_preds  = out_logits + (size_t)B_ * L_ * V_;    // [B,L]
  float* out_probs  = out_preds + (size_t)B_ * L_;          // [B,L,V]
  float* out_pemb   = out_probs + (size_t)B_ * L_ * V_;     // [B,L,E]

  float* DH = (float*)d_ws;                                 // 34 KB (64 KB reserved)
  float* Z  = (float*)((char*)d_ws + 65536);                // 128 MB; becomes G in place

  dh_kernel<<<1, 512, 0, stream>>>(W1, table, DH);
  dim3 g(65536 / GBM, H_ / GBN); // 512 x 4
  gemm_kernel<<<g, 256, 0, stream>>>(inputs, W1, b1, Z);
  lg_kernel<<<65536 / LG_ROWS, 256, 0, stream>>>(Z, DH, W2, b2, Z);
  chase_kernel<<<B_, 64, 0, stream>>>(Z, out_preds);
  epi_kernel<<<65536 / 256, 256, 0, stream>>>(Z, table, out_preds,
                                              out_logits, out_probs, out_pemb);
}

// Round 3
// 572.824 us; speedup vs baseline: 1.6289x; 1.2474x over previous
//
#include <hip/hip_runtime.h>
#include <math.h>

#define B_ 128
#define L_ 512
#define D_ 512
#define E_ 64
#define H_ 512
#define V_ 17

#define LOG2E_F 1.4426950408889634f
#define LN2_F   0.6931471805599453f

__device__ __forceinline__ float fast_tanh(float x) {
  // tanh(x) = 1 - 2/(1+e^{2x}); saturates correctly via exp2 over/underflow
  float e = __builtin_amdgcn_exp2f(x * (2.0f * LOG2E_F));
  return 1.0f - 2.0f * __builtin_amdgcn_rcpf(e + 1.0f);
}

// ---------------- DH/TD precompute: TD[v][h] = tanh(sum_e W1[h][D+e]*table[v][e]), row 0 zero
__global__ void dh_kernel(const float* __restrict__ W1, const float* __restrict__ table,
                          float* __restrict__ TD) {
  int h = threadIdx.x; // 512 threads
  float w[E_];
#pragma unroll
  for (int e = 0; e < E_; ++e) w[e] = W1[h * (D_ + E_) + D_ + e];
  TD[h] = 0.f; // v = 0 (PAD row is zero, tanh(0)=0)
  for (int v = 1; v < V_; ++v) {
    float acc = 0.f;
#pragma unroll
    for (int e = 0; e < E_; ++e) acc += w[e] * table[v * E_ + e];
    TD[v * H_ + h] = fast_tanh(acc);
  }
}

#define GBM 128
#define GBN 128
#define GBK 32
#define PITCH 20          // dwords per row: 16 data + 4 pad
#define SCALE_A 1024.0f
#define SCALE_W 256.0f
#define INV_SCALE (1.0f / (1024.0f * 256.0f))

typedef _Float16 half8 __attribute__((ext_vector_type(8)));
typedef __fp16 fp16x2 __attribute__((ext_vector_type(2)));
typedef float float4v __attribute__((ext_vector_type(4)));

union H8u { half8 h; fp16x2 p[4]; };

__device__ __forceinline__ uint4 split4(float4 v, float scale) {
  float a0 = v.x * scale, a1 = v.y * scale, a2 = v.z * scale, a3 = v.w * scale;
  _Float16 h0 = (_Float16)a0, h1 = (_Float16)a1, h2 = (_Float16)a2, h3 = (_Float16)a3;
  _Float16 l0 = (_Float16)(a0 - (float)h0), l1 = (_Float16)(a1 - (float)h1);
  _Float16 l2 = (_Float16)(a2 - (float)h2), l3 = (_Float16)(a3 - (float)h3);
  union { _Float16 h; unsigned short u; } c;
  unsigned int hu0, hu1, hu2, hu3, lu0, lu1, lu2, lu3;
  c.h = h0; hu0 = c.u; c.h = h1; hu1 = c.u; c.h = h2; hu2 = c.u; c.h = h3; hu3 = c.u;
  c.h = l0; lu0 = c.u; c.h = l1; lu1 = c.u; c.h = l2; lu2 = c.u; c.h = l3; lu3 = c.u;
  uint4 r;
  r.x = hu0 | (hu1 << 16);
  r.y = hu2 | (hu3 << 16);
  r.z = lu0 | (lu1 << 16);
  r.w = lu2 | (lu3 << 16);
  return r;
}

// ---------------- one-shot W1 split (first 512 cols), kills per-block re-split in gemm
__global__ __launch_bounds__(256)
void wsplit_kernel(const float* __restrict__ W1, unsigned int* __restrict__ WHI,
                   unsigned int* __restrict__ WLO) {
  const int idx = blockIdx.x * 256 + threadIdx.x;   // 65536 float4 groups
  const int row = idx >> 7, c4 = idx & 127;
  const float4 wv = *(const float4*)&W1[(size_t)row * (D_ + E_) + 4 * c4];
  const uint4 pw = split4(wv, SCALE_W);
  *(uint2*)&WHI[row * 256 + 2 * c4] = make_uint2(pw.x, pw.y);
  *(uint2*)&WLO[row * 256 + 2 * c4] = make_uint2(pw.z, pw.w);
}

// ---------------- split-fp16 3xMFMA GEMM; epilogue now writes TZ = tanh(A*W1^T + b1)
__global__ __launch_bounds__(256, 2)
void gemm_kernel(const float* __restrict__ A, const unsigned int* __restrict__ WHI,
                 const unsigned int* __restrict__ WLO,
                 const float* __restrict__ b1, float* __restrict__ TZ) {
  __shared__ unsigned int Ahi[GBM * PITCH], Alo[GBM * PITCH];
  __shared__ unsigned int Whi[GBN * PITCH], Wlo[GBN * PITCH];

  const int t = threadIdx.x;
  const int ln = t & 63, w = t >> 6;
  const int wm = w & 1, wn = w >> 1;
  const int mBase = blockIdx.x * GBM;
  const int nBase = blockIdx.y * GBN;
  const int lrow = ln & 15, lquad = ln >> 4;

  float4v acc[4][4];
#pragma unroll
  for (int i = 0; i < 4; ++i)
#pragma unroll
    for (int j = 0; j < 4; ++j) acc[i][j] = (float4v){0.f, 0.f, 0.f, 0.f};

  for (int kt = 0; kt < D_; kt += GBK) {
#pragma unroll
    for (int q = 0; q < 4; ++q) {
      const int idx = q * 256 + t;
      const int m = idx >> 3, f = idx & 7;
      const float4 av = *(const float4*)&A[(size_t)(mBase + m) * D_ + kt + 4 * f];
      const uint4 pa = split4(av, SCALE_A);
      *(uint2*)&Ahi[m * PITCH + 2 * f] = make_uint2(pa.x, pa.y);
      *(uint2*)&Alo[m * PITCH + 2 * f] = make_uint2(pa.z, pa.w);
      const uint2 wh = *(const uint2*)&WHI[(nBase + m) * 256 + (kt >> 1) + 2 * f];
      const uint2 wl = *(const uint2*)&WLO[(nBase + m) * 256 + (kt >> 1) + 2 * f];
      *(uint2*)&Whi[m * PITCH + 2 * f] = wh;
      *(uint2*)&Wlo[m * PITCH + 2 * f] = wl;
    }
    __syncthreads();

    half8 ah[4], al[4], bh[4], bl[4];
#pragma unroll
    for (int tm = 0; tm < 4; ++tm) {
      const int off = (wm * 64 + tm * 16 + lrow) * PITCH + 4 * lquad;
      ah[tm] = *(const half8*)&Ahi[off];
      al[tm] = *(const half8*)&Alo[off];
    }
#pragma unroll
    for (int tn = 0; tn < 4; ++tn) {
      const int off = (wn * 64 + tn * 16 + lrow) * PITCH + 4 * lquad;
      bh[tn] = *(const half8*)&Whi[off];
      bl[tn] = *(const half8*)&Wlo[off];
    }
#pragma unroll
    for (int tm = 0; tm < 4; ++tm)
#pragma unroll
      for (int tn = 0; tn < 4; ++tn) {
        acc[tm][tn] = __builtin_amdgcn_mfma_f32_16x16x32_f16(ah[tm], bh[tn], acc[tm][tn], 0, 0, 0);
        acc[tm][tn] = __builtin_amdgcn_mfma_f32_16x16x32_f16(ah[tm], bl[tn], acc[tm][tn], 0, 0, 0);
        acc[tm][tn] = __builtin_amdgcn_mfma_f32_16x16x32_f16(al[tm], bh[tn], acc[tm][tn], 0, 0, 0);
      }
    __syncthreads();
  }

#pragma unroll
  for (int tn = 0; tn < 4; ++tn) {
    const int col = nBase + wn * 64 + tn * 16 + lrow;
    const float bv = b1[col];
#pragma unroll
    for (int tm = 0; tm < 4; ++tm) {
      const int row0 = mBase + wm * 64 + tm * 16 + lquad * 4;
#pragma unroll
      for (int r = 0; r < 4; ++r)
        TZ[(size_t)(row0 + r) * H_ + col] = fast_tanh(acc[tm][tn][r] * INV_SCALE + bv);
    }
  }
}

// ---------------- lg_kernel: for 32 (b,t) rows, all 17 prev-pred variants.
// h = tanh(z+d) = (tz+td)/(1+tz*td); tz from gemm epilogue, td from dh_kernel.
// |td| <= ~0.1 (emb scale 0.02) so denominator in [0.9,1.1] -- no cancellation.
// a = 1024*h = (tz+td) * rcp((1+tz*td)*2^-10): 4 VALU + 1 trans per element
// (was 4 VALU + 2 trans). 8 waves / 512 thr -> 2 waves/SIMD (was 1).
// G layout unchanged: 17 rows x 20 pitch logits + next bytes at dword 352.
#define LG_ROWS 32
#define ZP 516   // f32 pitch: (516*4)%128=16 -> adjacent-lane slots differ
#define WP 260   // dword pitch for packed W2 halves

__global__ __launch_bounds__(512, 2)
void lg_kernel(const float* Zin, const float* __restrict__ TD,
               const float* __restrict__ W2, const float* __restrict__ b2,
               float* G) {               // G aliases Zin (no __restrict__!)
  __shared__ float sTZ[LG_ROWS * ZP];         // 66,048 B
  __shared__ float sTD[V_ * ZP];              // 35,088 B
  __shared__ unsigned int sW2hi[16 * WP];     // 16,640 B  (v = 0..15)
  __shared__ unsigned int sW2lo[16 * WP];     // 16,640 B
  __shared__ float sW16[H_];                  //  2,048 B  (v = 16, raw f32)
  __shared__ float sS[8][16][20];             // 10,240 B  per-wave transpose scratch
  __shared__ unsigned char nb[LG_ROWS][32];   //  1,024 B  next bytes
  // total 147,728 B -> 1 block/CU, 8 waves = 2/SIMD

  const int t = threadIdx.x;
  const int ln = t & 63, w = t >> 6;          // 8 waves
  const int bt0 = blockIdx.x * LG_ROWS;

  // ---- stage TZ tile (32 x 512)
#pragma unroll
  for (int i = 0; i < 8; ++i) {
    const int f = t + 512 * i;                    // 0..4095 float4 groups
    const int r = f >> 7, c = (f & 127) * 4;
    *(float4*)&sTZ[r * ZP + c] = *(const float4*)&Zin[(size_t)(bt0 + r) * H_ + c];
  }
  // ---- stage TD (17 x 512)
#pragma unroll
  for (int i = 0; i < 5; ++i) {
    const int f = t + 512 * i;
    if (f < (V_ * H_ / 4)) {
      const int r = f >> 7, c = (f & 127) * 4;
      *(float4*)&sTD[r * ZP + c] = *(const float4*)&TD[(size_t)r * H_ + c];
    }
  }
  // ---- stage + split W2 rows 0..15 (scaled x256), row 16 raw
#pragma unroll
  for (int i = 0; i < 4; ++i) {
    const int f = t + 512 * i;                    // 0..2047 = 16 rows x 128 f4
    const int r = f >> 7, c4 = f & 127;
    const float4 wv = *(const float4*)&W2[(size_t)r * H_ + 4 * c4];
    const uint4 pw = split4(wv, SCALE_W);
    *(uint2*)&sW2hi[r * WP + 2 * c4] = make_uint2(pw.x, pw.y);
    *(uint2*)&sW2lo[r * WP + 2 * c4] = make_uint2(pw.z, pw.w);
  }
  if (t < 128) *(float4*)&sW16[t * 4] = *(const float4*)&W2[(size_t)16 * H_ + t * 4];
  __syncthreads();

  const int lrow = ln & 15, lq = ln >> 4;
  const float b2a = b2[lrow];
  const float b2c = b2[16];

  // 34 tasks = 17 p x 2 row-groups, round-robin over 8 waves
  for (int task = w; task < 34; task += 8) {
    const int rg = (task >= 17) ? 1 : 0;
    const int p = task - rg * 17;
    const int rbase = rg * 16;

    float4v acc0 = (float4v){0.f, 0.f, 0.f, 0.f};
    float p16 = 0.f;
    for (int kt = 0; kt < H_; kt += 32) {
      const float* zr = &sTZ[(rbase + lrow) * ZP + kt + lq * 8];
      const float* dr = &sTD[p * ZP + kt + lq * 8];   // broadcast within 16 lanes
      float a[8];
#pragma unroll
      for (int j = 0; j < 8; ++j) {
        const float tz = zr[j], td = dr[j];
        // a = 1024*tanh(z+d) = (tz+td) * (1024/(1+tz*td))
        const float r = __builtin_amdgcn_rcpf(fmaf(tz, td, 1.0f) * 0.0009765625f);
        a[j] = (tz + td) * r;
      }
      H8u uh, ul;
#pragma unroll
      for (int jj = 0; jj < 4; ++jj) {
        const fp16x2 hp = __builtin_amdgcn_cvt_pkrtz(a[2 * jj], a[2 * jj + 1]);
        uh.p[jj] = hp;
        ul.p[jj] = __builtin_amdgcn_cvt_pkrtz(a[2 * jj] - (float)hp.x,
                                              a[2 * jj + 1] - (float)hp.y);
      }
      const int wo = (kt >> 1) + lq * 4;
      const half8 bh0 = *(const half8*)&sW2hi[lrow * WP + wo];
      const half8 bl0 = *(const half8*)&sW2lo[lrow * WP + wo];
      acc0 = __builtin_amdgcn_mfma_f32_16x16x32_f16(uh.h, bh0, acc0, 0, 0, 0);
      acc0 = __builtin_amdgcn_mfma_f32_16x16x32_f16(uh.h, bl0, acc0, 0, 0, 0);
      acc0 = __builtin_amdgcn_mfma_f32_16x16x32_f16(ul.h, bh0, acc0, 0, 0, 0);
      const float* wr = &sW16[kt + lq * 8];           // uniform across lrow
#pragma unroll
      for (int j = 0; j < 8; ++j) p16 = fmaf(a[j], wr[j], p16);
    }
    // v16: reduce over the 4 k-quadrant lane groups
    p16 += __shfl_xor(p16, 16, 64);
    p16 += __shfl_xor(p16, 32, 64);
    // transpose C quadrant through LDS: C[row=lq*4+r][col=lrow]
#pragma unroll
    for (int r = 0; r < 4; ++r)
      sS[w][lq * 4 + r][lrow] = acc0[r] * INV_SCALE + b2a;
    if (ln < 16) {                                 // lane == row, lq==0
      float va[17];
      const float4 q0 = *(const float4*)&sS[w][ln][0];
      const float4 q1 = *(const float4*)&sS[w][ln][4];
      const float4 q2 = *(const float4*)&sS[w][ln][8];
      const float4 q3 = *(const float4*)&sS[w][ln][12];
      va[0] = q0.x; va[1] = q0.y; va[2] = q0.z; va[3] = q0.w;
      va[4] = q1.x; va[5] = q1.y; va[6] = q1.z; va[7] = q1.w;
      va[8] = q2.x; va[9] = q2.y; va[10] = q2.z; va[11] = q2.w;
      va[12] = q3.x; va[13] = q3.y; va[14] = q3.z; va[15] = q3.w;
      va[16] = p16 * (1.0f / 1024.0f) + b2c;
      float m = va[0]; int am = 0;
#pragma unroll
      for (int i = 1; i < 17; ++i) if (va[i] > m) { m = va[i]; am = i; }
      float* gs = &G[(size_t)(bt0 + rbase + ln) * H_ + p * 20];
      *(float4*)&gs[0] = q0; *(float4*)&gs[4] = q1;
      *(float4*)&gs[8] = q2; *(float4*)&gs[12] = q3;
      gs[16] = va[16];
      nb[rbase + ln][p] = (unsigned char)am;
    }
  }
  __syncthreads();
  // pack next bytes into dwords 352..356 of each slot
  if (t < 160) {
    const int row = t / 5, d = t % 5;
    ((unsigned int*)&G[(size_t)(bt0 + row) * H_ + 352])[d] =
        *(const unsigned int*)&nb[row][d * 4];
  }
}

// ---------------- chase_kernel: the recurrence is a byte-table walk.
__global__ __launch_bounds__(64, 1)
void chase_kernel(const float* __restrict__ G, float* __restrict__ out_preds) {
  __shared__ unsigned char nxt[L_ * 32];   // 16 KB
  const int b = blockIdx.x, ln = threadIdx.x;
#pragma unroll
  for (int i = 0; i < 8; ++i) {
    const int tt = ln + 64 * i;
    const unsigned int* src = (const unsigned int*)&G[((size_t)b * L_ + tt) * H_ + 352];
    *(uint4*)&nxt[tt * 32] = *(const uint4*)src;
    *(unsigned int*)&nxt[tt * 32 + 16] = src[4];
  }
  __syncthreads();
  int pred = 0;
  float* op = out_preds + (size_t)b * L_;
  for (int tt = 0; tt < L_; ++tt) {
    pred = nxt[tt * 32 + pred];
    if (ln == 0) op[tt] = (float)pred;
  }
}

// ---------------- epi_kernel: embarrassingly-parallel outputs from G + preds.
__global__ __launch_bounds__(256)
void epi_kernel(const float* __restrict__ G, const float* __restrict__ table,
                const float* __restrict__ preds,
                float* __restrict__ out_logits, float* __restrict__ out_probs,
                float* __restrict__ out_pemb) {
  const int bt = blockIdx.x * 256 + threadIdx.x;
  const int tt = bt & (L_ - 1);
  const int p = (tt == 0) ? 0 : (int)preds[bt - 1];
  const float* g = &G[(size_t)bt * H_ + p * 20];
  float va[17];
  {
    const float4 q0 = *(const float4*)&g[0];
    const float4 q1 = *(const float4*)&g[4];
    const float4 q2 = *(const float4*)&g[8];
    const float4 q3 = *(const float4*)&g[12];
    va[0] = q0.x; va[1] = q0.y; va[2] = q0.z; va[3] = q0.w;
    va[4] = q1.x; va[5] = q1.y; va[6] = q1.z; va[7] = q1.w;
    va[8] = q2.x; va[9] = q2.y; va[10] = q2.z; va[11] = q2.w;
    va[12] = q3.x; va[13] = q3.y; va[14] = q3.z; va[15] = q3.w;
    va[16] = g[16];
  }
  float m = va[0];
#pragma unroll
  for (int i = 1; i < 17; ++i) m = fmaxf(m, va[i]);
  float s = 0.f;
#pragma unroll
  for (int i = 0; i < 17; ++i) s += __builtin_amdgcn_exp2f((va[i] - m) * LOG2E_F);
  const float lse = __builtin_amdgcn_logf(s) * LN2_F;
  float* lo = out_logits + (size_t)bt * V_;
  float* pb = out_probs + (size_t)bt * V_;
#pragma unroll
  for (int i = 0; i < 17; ++i) { lo[i] = va[i]; pb[i] = va[i] - m - lse; }
  const int pr = (int)preds[bt];
  float* pe = out_pemb + (size_t)bt * E_;
  if (pr == 0) {
#pragma unroll
    for (int i = 0; i < 16; ++i) *(float4*)&pe[4 * i] = (float4){0.f, 0.f, 0.f, 0.f};
  } else {
    const float* tr = &table[(size_t)pr * E_];
#pragma unroll
    for (int i = 0; i < 16; ++i) *(float4*)&pe[4 * i] = *(const float4*)&tr[4 * i];
  }
}

extern "C" void kernel_launch(void* const* d_in, const int* in_sizes, int n_in,
                              void* d_out, int out_size, void* d_ws, size_t ws_size,
                              hipStream_t stream) {
  const float* inputs = (const float*)d_in[0];
  const float* table  = (const float*)d_in[1];
  const float* W1     = (const float*)d_in[2];
  const float* b1     = (const float*)d_in[3];
  const float* W2     = (const float*)d_in[4];
  const float* b2     = (const float*)d_in[5];

  float* out = (float*)d_out;
  float* out_logits = out;                                  // [B,L,V]
  float* out_preds  = out_logits + (size_t)B_ * L_ * V_;    // [B,L]
  float* out_probs  = out_preds + (size_t)B_ * L_;          // [B,L,V]
  float* out_pemb   = out_probs + (size_t)B_ * L_ * V_;     // [B,L,E]

  float* TD = (float*)d_ws;                                 // 34 KB (64 KB reserved)
  float* TZ = (float*)((char*)d_ws + 65536);                // 128 MB; becomes G in place

  // W1-split scratch lives in out_pemb (1 MB < 16.8 MB); consumed by gemm,
  // overwritten by epi at the very end -- stream-ordered, safe.
  unsigned int* WHI = (unsigned int*)out_pemb;
  unsigned int* WLO = WHI + 512 * 256;

  dh_kernel<<<1, 512, 0, stream>>>(W1, table, TD);
  wsplit_kernel<<<256, 256, 0, stream>>>(W1, WHI, WLO);
  dim3 g(65536 / GBM, H_ / GBN); // 512 x 4
  gemm_kernel<<<g, 256, 0, stream>>>(inputs, WHI, WLO, b1, TZ);
  lg_kernel<<<65536 / LG_ROWS, 512, 0, stream>>>(TZ, TD, W2, b2, TZ);
  chase_kernel<<<B_, 64, 0, stream>>>(TZ, out_preds);
  epi_kernel<<<65536 / 256, 256, 0, stream>>>(TZ, table, out_preds,
                                              out_logits, out_probs, out_pemb);
}

// Round 5
// 502.433 us; speedup vs baseline: 1.8571x; 1.1401x over previous
//
#include <hip/hip_runtime.h>
#include <math.h>

#define B_ 128
#define L_ 512
#define D_ 512
#define E_ 64
#define H_ 512
#define V_ 17

#define LOG2E_F 1.4426950408889634f
#define LN2_F   0.6931471805599453f

__device__ __forceinline__ float fast_tanh(float x) {
  float e = __builtin_amdgcn_exp2f(x * (2.0f * LOG2E_F));
  return 1.0f - 2.0f * __builtin_amdgcn_rcpf(e + 1.0f);
}

// ---------------- TD precompute: TD[v][h] = tanh(sum_e W1[h][D+e]*table[v][e]), row 0 zero
__global__ void dh_kernel(const float* __restrict__ W1, const float* __restrict__ table,
                          float* __restrict__ TD) {
  int h = threadIdx.x; // 512 threads
  float w[E_];
#pragma unroll
  for (int e = 0; e < E_; ++e) w[e] = W1[h * (D_ + E_) + D_ + e];
  TD[h] = 0.f;
  for (int v = 1; v < V_; ++v) {
    float acc = 0.f;
#pragma unroll
    for (int e = 0; e < E_; ++e) acc += w[e] * table[v * E_ + e];
    TD[v * H_ + h] = fast_tanh(acc);
  }
}

#define PITCH 20          // dwords per LDS row: 16 data + 4 pad
#define SCALE_A 1024.0f
#define SCALE_W 256.0f
#define INV_SCALE (1.0f / (1024.0f * 256.0f))

typedef _Float16 half8 __attribute__((ext_vector_type(8)));
typedef __fp16 fp16x2 __attribute__((ext_vector_type(2)));
typedef float float4v __attribute__((ext_vector_type(4)));

union H8c { half8 h; fp16x2 q[4]; unsigned int u[4]; uint4 u4; };

__device__ __forceinline__ uint4 split4(float4 v, float scale) {
  float a0 = v.x * scale, a1 = v.y * scale, a2 = v.z * scale, a3 = v.w * scale;
  _Float16 h0 = (_Float16)a0, h1 = (_Float16)a1, h2 = (_Float16)a2, h3 = (_Float16)a3;
  _Float16 l0 = (_Float16)(a0 - (float)h0), l1 = (_Float16)(a1 - (float)h1);
  _Float16 l2 = (_Float16)(a2 - (float)h2), l3 = (_Float16)(a3 - (float)h3);
  union { _Float16 h; unsigned short u; } c;
  unsigned int hu0, hu1, hu2, hu3, lu0, lu1, lu2, lu3;
  c.h = h0; hu0 = c.u; c.h = h1; hu1 = c.u; c.h = h2; hu2 = c.u; c.h = h3; hu3 = c.u;
  c.h = l0; lu0 = c.u; c.h = l1; lu1 = c.u; c.h = l2; lu2 = c.u; c.h = l3; lu3 = c.u;
  uint4 r;
  r.x = hu0 | (hu1 << 16);
  r.y = hu2 | (hu3 << 16);
  r.z = lu0 | (lu1 << 16);
  r.w = lu2 | (lu3 << 16);
  return r;
}

__device__ __forceinline__ uint2 pack4h(_Float16 a, _Float16 b, _Float16 c, _Float16 d) {
  union { _Float16 h; unsigned short u; } x;
  unsigned int lo, hi;
  x.h = a; lo = x.u; x.h = b; lo |= ((unsigned int)x.u) << 16;
  x.h = c; hi = x.u; x.h = d; hi |= ((unsigned int)x.u) << 16;
  return make_uint2(lo, hi);
}

// ---------------- one-shot W1 split (first 512 cols)
__global__ __launch_bounds__(256)
void wsplit_kernel(const float* __restrict__ W1, unsigned int* __restrict__ WHI,
                   unsigned int* __restrict__ WLO) {
  const int idx = blockIdx.x * 256 + threadIdx.x;   // 65536 float4 groups
  const int row = idx >> 7, c4 = idx & 127;
  const float4 wv = *(const float4*)&W1[(size_t)row * (D_ + E_) + 4 * c4];
  const uint4 pw = split4(wv, SCALE_W);
  *(uint2*)&WHI[row * 256 + 2 * c4] = make_uint2(pw.x, pw.y);
  *(uint2*)&WLO[row * 256 + 2 * c4] = make_uint2(pw.z, pw.w);
}

// ---------------- split-fp16 3xMFMA GEMM, full-N blocks: TZ = tanh(A*W1^T + b1)
// 512 blocks x 512 thr; block = 128m x 512n. A staged+split EXACTLY ONCE per
// element (was 4x); W from presplit global (pure uint4 copies, zero VALU).
// Wave-tile 64m x 128n: acc[4][8] f32x4 = 128 VGPR.
__global__ __launch_bounds__(512, 2)
void gemm_kernel(const float* __restrict__ A, const unsigned int* __restrict__ WHI,
                 const unsigned int* __restrict__ WLO,
                 const float* __restrict__ b1, float* __restrict__ TZ) {
  __shared__ unsigned int Ahi[128 * PITCH], Alo[128 * PITCH];   // 10 KB each
  __shared__ unsigned int Whi[512 * PITCH], Wlo[512 * PITCH];   // 40 KB each

  const int t = threadIdx.x;
  const int ln = t & 63, w = t >> 6;
  const int wm = w & 1, wn = w >> 1;          // 2 m-halves x 4 n-quarters
  const int mBase = blockIdx.x * 128;
  const int lrow = ln & 15, lquad = ln >> 4;

  float4v acc[4][8];
#pragma unroll
  for (int i = 0; i < 4; ++i)
#pragma unroll
    for (int j = 0; j < 8; ++j) acc[i][j] = (float4v){0.f, 0.f, 0.f, 0.f};

  for (int kt = 0; kt < D_; kt += 32) {
    // stage A (128 x 32 f32 -> split once)
#pragma unroll
    for (int q = 0; q < 2; ++q) {
      const int idx = q * 512 + t;              // 0..1023
      const int m = idx >> 3, f = idx & 7;
      const float4 av = *(const float4*)&A[(size_t)(mBase + m) * D_ + kt + 4 * f];
      const uint4 pa = split4(av, SCALE_A);
      *(uint2*)&Ahi[m * PITCH + 2 * f] = make_uint2(pa.x, pa.y);
      *(uint2*)&Alo[m * PITCH + 2 * f] = make_uint2(pa.z, pa.w);
    }
    // stage W presplit (512 rows x 16 dwords each, hi+lo)
#pragma unroll
    for (int q = 0; q < 4; ++q) {
      const int idx = q * 512 + t;              // 0..2047
      const int n = idx >> 2, d4 = (idx & 3) * 4;
      *(uint4*)&Whi[n * PITCH + d4] = *(const uint4*)&WHI[n * 256 + (kt >> 1) + d4];
      *(uint4*)&Wlo[n * PITCH + d4] = *(const uint4*)&WLO[n * 256 + (kt >> 1) + d4];
    }
    __syncthreads();

    half8 ah[4], al[4];
#pragma unroll
    for (int tm = 0; tm < 4; ++tm) {
      const int off = (wm * 64 + tm * 16 + lrow) * PITCH + 4 * lquad;
      ah[tm] = *(const half8*)&Ahi[off];
      al[tm] = *(const half8*)&Alo[off];
    }
#pragma unroll
    for (int tn = 0; tn < 8; ++tn) {
      const int off = (wn * 128 + tn * 16 + lrow) * PITCH + 4 * lquad;
      const half8 bh = *(const half8*)&Whi[off];
      const half8 bl = *(const half8*)&Wlo[off];
#pragma unroll
      for (int tm = 0; tm < 4; ++tm) {
        acc[tm][tn] = __builtin_amdgcn_mfma_f32_16x16x32_f16(ah[tm], bh, acc[tm][tn], 0, 0, 0);
        acc[tm][tn] = __builtin_amdgcn_mfma_f32_16x16x32_f16(ah[tm], bl, acc[tm][tn], 0, 0, 0);
        acc[tm][tn] = __builtin_amdgcn_mfma_f32_16x16x32_f16(al[tm], bh, acc[tm][tn], 0, 0, 0);
      }
    }
    __syncthreads();
  }

#pragma unroll
  for (int tn = 0; tn < 8; ++tn) {
    const int col = wn * 128 + tn * 16 + lrow;
    const float bv = b1[col];
#pragma unroll
    for (int tm = 0; tm < 4; ++tm) {
      const int row0 = mBase + wm * 64 + tm * 16 + lquad * 4;
#pragma unroll
      for (int r = 0; r < 4; ++r)
        TZ[(size_t)(row0 + r) * H_ + col] = fast_tanh(acc[tm][tn][r] * INV_SCALE + bv);
    }
  }
}

// ---------------- lg_kernel v2: Taylor-corrected variants, f16 tables, kt-outer.
// h_p = tz + u*td_p*(1-q+q^2), q = tz*td_p (|td|<=0.044 -> remainder ~1e-6).
// Scaled A-operand: As = 1024*h = ahi + (alo + dl), dl = u1024*td*(1-q+q^2),
// folded into the low split -> same 3-MFMA precision class as before.
// Per (p,kt) inner work: 1 LDS + 6 pk-f16 + 3 MFMA + 4 fdot2 (was ~90 slots).
// G layout unchanged: 17 rows x 20 pitch logits + next bytes at dword 352.
#define LGR 32
#define AP 520   // half-pitch A-tables: 1040 B/row == 4 mod 32 banks (2-way, free)
#define WP 260   // dword pitch for packed W2 halves

__global__ __launch_bounds__(512, 2)
void lg_kernel(const float* Zin, const float* __restrict__ TD,
               const float* __restrict__ W2, const float* __restrict__ b2,
               float* G) {               // G aliases Zin (no __restrict__!)
  __shared__ __align__(16) unsigned int sAhiD[LGR * AP / 2];   // 33,280 B
  __shared__ __align__(16) unsigned int sAloD[LGR * AP / 2];   // 33,280 B
  __shared__ __align__(16) unsigned int sUD[LGR * AP / 2];     // 33,280 B
  __shared__ __align__(16) unsigned int sTDd[V_ * 256];        // 17,408 B
  __shared__ __align__(16) unsigned int sW2hi[16 * WP];        // 16,640 B
  __shared__ __align__(16) unsigned int sW2lo[16 * WP];        // 16,640 B
  __shared__ __align__(16) unsigned int sW16hi[256];           //  1,024 B
  __shared__ __align__(16) unsigned int sW16lo[256];           //  1,024 B
  __shared__ __align__(16) float sS[8][16][20];                // 10,240 B
  __shared__ __align__(16) float sV16b[32];                    //    128 B
  __shared__ __align__(16) unsigned char nb[LGR][20];          //    640 B
  // total 163,584 B <= 160 KB -> 1 block/CU, 8 waves = 2/SIMD

  const int t = threadIdx.x;
  const int ln = t & 63, w = t >> 6;          // 8 waves
  const int bt0 = blockIdx.x * LGR;

  // ---- A-tables from Zin (tz f32): ahi/alo = split(1024*tz), u1024 = 1024*(1-tz^2)
#pragma unroll
  for (int i = 0; i < 8; ++i) {
    const int f = t + 512 * i;                    // 0..4095 = 32 rows x 128 f4
    const int r = f >> 7, c4 = f & 127;
    const float4 z = *(const float4*)&Zin[(size_t)(bt0 + r) * H_ + 4 * c4];
    const float a0 = 1024.f * z.x, a1 = 1024.f * z.y, a2 = 1024.f * z.z, a3 = 1024.f * z.w;
    const _Float16 h0 = (_Float16)a0, h1 = (_Float16)a1, h2 = (_Float16)a2, h3 = (_Float16)a3;
    const _Float16 l0 = (_Float16)(a0 - (float)h0), l1 = (_Float16)(a1 - (float)h1);
    const _Float16 l2 = (_Float16)(a2 - (float)h2), l3 = (_Float16)(a3 - (float)h3);
    const _Float16 u0 = (_Float16)fmaf(-a0, z.x, 1024.f), u1 = (_Float16)fmaf(-a1, z.y, 1024.f);
    const _Float16 u2 = (_Float16)fmaf(-a2, z.z, 1024.f), u3 = (_Float16)fmaf(-a3, z.w, 1024.f);
    const int o = r * (AP / 2) + 2 * c4;
    *(uint2*)&sAhiD[o] = pack4h(h0, h1, h2, h3);
    *(uint2*)&sAloD[o] = pack4h(l0, l1, l2, l3);
    *(uint2*)&sUD[o]   = pack4h(u0, u1, u2, u3);
  }
  // ---- TD f16 (17 x 512)
#pragma unroll
  for (int i = 0; i < 5; ++i) {
    const int f = t + 512 * i;
    if (f < V_ * 128) {
      const int r = f >> 7, c4 = f & 127;
      const float4 d = *(const float4*)&TD[(size_t)r * H_ + 4 * c4];
      *(uint2*)&sTDd[r * 256 + 2 * c4] =
          pack4h((_Float16)d.x, (_Float16)d.y, (_Float16)d.z, (_Float16)d.w);
    }
  }
  // ---- W2 rows 0..15 split (x256); row 16 hi/lo split (x1)
#pragma unroll
  for (int i = 0; i < 4; ++i) {
    const int f = t + 512 * i;                    // 0..2047 = 16 rows x 128 f4
    const int r = f >> 7, c4 = f & 127;
    const float4 wv = *(const float4*)&W2[(size_t)r * H_ + 4 * c4];
    const uint4 pw = split4(wv, SCALE_W);
    *(uint2*)&sW2hi[r * WP + 2 * c4] = make_uint2(pw.x, pw.y);
    *(uint2*)&sW2lo[r * WP + 2 * c4] = make_uint2(pw.z, pw.w);
  }
  if (t < 128) {
    const float4 wv = *(const float4*)&W2[(size_t)16 * H_ + 4 * t];
    const uint4 pw = split4(wv, 1.0f);
    *(uint2*)&sW16hi[2 * t] = make_uint2(pw.x, pw.y);
    *(uint2*)&sW16lo[2 * t] = make_uint2(pw.z, pw.w);
  }
  __syncthreads();

  // ---- base16[row] = sum_h (ahi+alo)*w16  (p-independent part of v16, scaled 1024)
  {
    const int row = t >> 4, seg = t & 15;
    const unsigned int* Ah = &sAhiD[row * (AP / 2) + seg * 16];
    const unsigned int* Al = &sAloD[row * (AP / 2) + seg * 16];
    const unsigned int* Wh = &sW16hi[seg * 16];
    const unsigned int* Wl = &sW16lo[seg * 16];
    float s = 0.f;
#pragma unroll
    for (int j = 0; j < 16; ++j) {
      const fp16x2 a = __builtin_bit_cast(fp16x2, Ah[j]);
      const fp16x2 l = __builtin_bit_cast(fp16x2, Al[j]);
      const fp16x2 wh = __builtin_bit_cast(fp16x2, Wh[j]);
      const fp16x2 wl = __builtin_bit_cast(fp16x2, Wl[j]);
      s = __builtin_amdgcn_fdot2(a, wh, s, false);
      s = __builtin_amdgcn_fdot2(l, wh, s, false);
      s = __builtin_amdgcn_fdot2(a, wl, s, false);
    }
    ((float*)sS)[row * 16 + seg] = s;
  }
  __syncthreads();
  if (t < 32) {
    float s = 0.f;
#pragma unroll
    for (int j = 0; j < 16; ++j) s += ((float*)sS)[t * 16 + j];
    sV16b[t] = s;
  }
  __syncthreads();

  const int lrow = ln & 15, lq = ln >> 4;
  const int rg = w & 1, pq = w >> 1;            // row-group, p-residue
  const int rbase = rg * 16;
  const float b2a = b2[lrow];
  const float b2c = b2[16];

  float4v acc[5];
  float p16s[5];
#pragma unroll
  for (int pi = 0; pi < 5; ++pi) { acc[pi] = (float4v){0.f, 0.f, 0.f, 0.f}; p16s[pi] = 0.f; }

  const _Float16* Ahalf = (const _Float16*)sAhiD;
  const _Float16* Alhalf = (const _Float16*)sAloD;
  const _Float16* Uhalf = (const _Float16*)sUD;
  const _Float16* TDhalf = (const _Float16*)sTDd;

  for (int kt = 0; kt < H_; kt += 32) {
    const int ho = kt + lq * 8;
    const half8 ahi = *(const half8*)(Ahalf + (rbase + lrow) * AP + ho);
    const half8 alo = *(const half8*)(Alhalf + (rbase + lrow) * AP + ho);
    const half8 uu  = *(const half8*)(Uhalf + (rbase + lrow) * AP + ho);
    const half8 tzv = ahi * (_Float16)0.0009765625f;   // exact: scale by 2^-10
    H8c W16f; W16f.u4 = *(const uint4*)&sW16hi[ho >> 1];
    const int wo = lrow * WP + (kt >> 1) + lq * 4;
    const half8 bh0 = *(const half8*)&sW2hi[wo];
    const half8 bl0 = *(const half8*)&sW2lo[wo];
#pragma unroll
    for (int pi = 0; pi < 5; ++pi) {
      const int p = pq + 4 * pi;
      if (p < V_) {
        const half8 td = *(const half8*)(TDhalf + p * 512 + ho);
        const half8 q = tzv * td;
        const half8 s = q * q + ((_Float16)1.0f - q);
        const half8 dl = uu * (td * s);                // delta, scaled x1024
        const half8 alp = alo + dl;
        acc[pi] = __builtin_amdgcn_mfma_f32_16x16x32_f16(ahi, bh0, acc[pi], 0, 0, 0);
        acc[pi] = __builtin_amdgcn_mfma_f32_16x16x32_f16(ahi, bl0, acc[pi], 0, 0, 0);
        acc[pi] = __builtin_amdgcn_mfma_f32_16x16x32_f16(alp, bh0, acc[pi], 0, 0, 0);
        H8c DL; DL.h = dl;
        p16s[pi] = __builtin_amdgcn_fdot2(DL.q[0], W16f.q[0], p16s[pi], false);
        p16s[pi] = __builtin_amdgcn_fdot2(DL.q[1], W16f.q[1], p16s[pi], false);
        p16s[pi] = __builtin_amdgcn_fdot2(DL.q[2], W16f.q[2], p16s[pi], false);
        p16s[pi] = __builtin_amdgcn_fdot2(DL.q[3], W16f.q[3], p16s[pi], false);
      }
    }
  }

#pragma unroll
  for (int pi = 0; pi < 5; ++pi) {
    const int p = pq + 4 * pi;
    if (p < V_) {
      float p16 = p16s[pi];
      p16 += __shfl_xor(p16, 16, 64);
      p16 += __shfl_xor(p16, 32, 64);
#pragma unroll
      for (int r = 0; r < 4; ++r)
        sS[w][lq * 4 + r][lrow] = acc[pi][r] * INV_SCALE + b2a;
      if (ln < 16) {
        float va[17];
        const float4 q0 = *(const float4*)&sS[w][ln][0];
        const float4 q1 = *(const float4*)&sS[w][ln][4];
        const float4 q2 = *(const float4*)&sS[w][ln][8];
        const float4 q3 = *(const float4*)&sS[w][ln][12];
        va[0] = q0.x; va[1] = q0.y; va[2] = q0.z; va[3] = q0.w;
        va[4] = q1.x; va[5] = q1.y; va[6] = q1.z; va[7] = q1.w;
        va[8] = q2.x; va[9] = q2.y; va[10] = q2.z; va[11] = q2.w;
        va[12] = q3.x; va[13] = q3.y; va[14] = q3.z; va[15] = q3.w;
        va[16] = (sV16b[rbase + ln] + p16) * 0.0009765625f + b2c;
        float m = va[0]; int am = 0;
#pragma unroll
        for (int i = 1; i < 17; ++i) if (va[i] > m) { m = va[i]; am = i; }
        float* gs = &G[(size_t)(bt0 + rbase + ln) * H_ + p * 20];
        *(float4*)&gs[0] = q0; *(float4*)&gs[4] = q1;
        *(float4*)&gs[8] = q2; *(float4*)&gs[12] = q3;
        gs[16] = va[16];
        nb[rbase + ln][p] = (unsigned char)am;
      }
    }
  }
  __syncthreads();
  // pack next bytes into dwords 352..356 of each slot
  if (t < 160) {
    const int row = t / 5, d = t % 5;
    ((unsigned int*)&G[(size_t)(bt0 + row) * H_ + 352])[d] =
        *(const unsigned int*)&nb[row][d * 4];
  }
}

// ---------------- chase_kernel: the recurrence is a byte-table walk.
__global__ __launch_bounds__(64, 1)
void chase_kernel(const float* __restrict__ G, float* __restrict__ out_preds) {
  __shared__ unsigned char nxt[L_ * 32];   // 16 KB
  const int b = blockIdx.x, ln = threadIdx.x;
#pragma unroll
  for (int i = 0; i < 8; ++i) {
    const int tt = ln + 64 * i;
    const unsigned int* src = (const unsigned int*)&G[((size_t)b * L_ + tt) * H_ + 352];
    *(uint4*)&nxt[tt * 32] = *(const uint4*)src;
    *(unsigned int*)&nxt[tt * 32 + 16] = src[4];
  }
  __syncthreads();
  int pred = 0;
  float* op = out_preds + (size_t)b * L_;
  for (int tt = 0; tt < L_; ++tt) {
    pred = nxt[tt * 32 + pred];
    if (ln == 0) op[tt] = (float)pred;
  }
}

// ---------------- epi_kernel: embarrassingly-parallel outputs from G + preds.
__global__ __launch_bounds__(256)
void epi_kernel(const float* __restrict__ G, const float* __restrict__ table,
                const float* __restrict__ preds,
                float* __restrict__ out_logits, float* __restrict__ out_probs,
                float* __restrict__ out_pemb) {
  const int bt = blockIdx.x * 256 + threadIdx.x;
  const int tt = bt & (L_ - 1);
  const int p = (tt == 0) ? 0 : (int)preds[bt - 1];
  const float* g = &G[(size_t)bt * H_ + p * 20];
  float va[17];
  {
    const float4 q0 = *(const float4*)&g[0];
    const float4 q1 = *(const float4*)&g[4];
    const float4 q2 = *(const float4*)&g[8];
    const float4 q3 = *(const float4*)&g[12];
    va[0] = q0.x; va[1] = q0.y; va[2] = q0.z; va[3] = q0.w;
    va[4] = q1.x; va[5] = q1.y; va[6] = q1.z; va[7] = q1.w;
    va[8] = q2.x; va[9] = q2.y; va[10] = q2.z; va[11] = q2.w;
    va[12] = q3.x; va[13] = q3.y; va[14] = q3.z; va[15] = q3.w;
    va[16] = g[16];
  }
  float m = va[0];
#pragma unroll
  for (int i = 1; i < 17; ++i) m = fmaxf(m, va[i]);
  float s = 0.f;
#pragma unroll
  for (int i = 0; i < 17; ++i) s += __builtin_amdgcn_exp2f((va[i] - m) * LOG2E_F);
  const float lse = __builtin_amdgcn_logf(s) * LN2_F;
  float* lo = out_logits + (size_t)bt * V_;
  float* pb = out_probs + (size_t)bt * V_;
#pragma unroll
  for (int i = 0; i < 17; ++i) { lo[i] = va[i]; pb[i] = va[i] - m - lse; }
  const int pr = (int)preds[bt];
  float* pe = out_pemb + (size_t)bt * E_;
  if (pr == 0) {
#pragma unroll
    for (int i = 0; i < 16; ++i) *(float4*)&pe[4 * i] = (float4){0.f, 0.f, 0.f, 0.f};
  } else {
    const float* tr = &table[(size_t)pr * E_];
#pragma unroll
    for (int i = 0; i < 16; ++i) *(float4*)&pe[4 * i] = *(const float4*)&tr[4 * i];
  }
}

extern "C" void kernel_launch(void* const* d_in, const int* in_sizes, int n_in,
                              void* d_out, int out_size, void* d_ws, size_t ws_size,
                              hipStream_t stream) {
  const float* inputs = (const float*)d_in[0];
  const float* table  = (const float*)d_in[1];
  const float* W1     = (const float*)d_in[2];
  const float* b1     = (const float*)d_in[3];
  const float* W2     = (const float*)d_in[4];
  const float* b2     = (const float*)d_in[5];

  float* out = (float*)d_out;
  float* out_logits = out;                                  // [B,L,V]
  float* out_preds  = out_logits + (size_t)B_ * L_ * V_;    // [B,L]
  float* out_probs  = out_preds + (size_t)B_ * L_;          // [B,L,V]
  float* out_pemb   = out_probs + (size_t)B_ * L_ * V_;     // [B,L,E]

  float* TD = (float*)d_ws;                                 // 34 KB (64 KB reserved)
  float* TZ = (float*)((char*)d_ws + 65536);                // 128 MB; becomes G in place

  // W1-split scratch in out_pemb (1 MB < 16.8 MB); consumed by gemm,
  // overwritten by epi at the very end -- stream-ordered, safe.
  unsigned int* WHI = (unsigned int*)out_pemb;
  unsigned int* WLO = WHI + 512 * 256;

  dh_kernel<<<1, 512, 0, stream>>>(W1, table, TD);
  wsplit_kernel<<<256, 256, 0, stream>>>(W1, WHI, WLO);
  gemm_kernel<<<512, 512, 0, stream>>>(inputs, WHI, WLO, b1, TZ);
  lg_kernel<<<65536 / LGR, 512, 0, stream>>>(TZ, TD, W2, b2, TZ);
  chase_kernel<<<B_, 64, 0, stream>>>(TZ, out_preds);
  epi_kernel<<<65536 / 256, 256, 0, stream>>>(TZ, table, out_preds,
                                              out_logits, out_probs, out_pemb);
}

// Round 7
// 463.248 us; speedup vs baseline: 2.0141x; 1.0846x over previous
//
#include <hip/hip_runtime.h>
#include <math.h>

#define B_ 128
#define L_ 512
#define D_ 512
#define E_ 64
#define H_ 512
#define V_ 17

#define LOG2E_F 1.4426950408889634f
#define LN2_F   0.6931471805599453f

__device__ __forceinline__ float fast_tanh(float x) {
  float e = __builtin_amdgcn_exp2f(x * (2.0f * LOG2E_F));
  return 1.0f - 2.0f * __builtin_amdgcn_rcpf(e + 1.0f);
}

#define PITCH 20          // dwords per LDS row: 16 data + 4 pad
#define SCALE_A 1024.0f
#define SCALE_W 256.0f
#define INV_SCALE (1.0f / (1024.0f * 256.0f))
#define NC 304            // padded corr columns (19 tiles); 289 = 17x17 used

typedef _Float16 half8 __attribute__((ext_vector_type(8)));
typedef float float4v __attribute__((ext_vector_type(4)));

__device__ __forceinline__ uint4 split4(float4 v, float scale) {
  float a0 = v.x * scale, a1 = v.y * scale, a2 = v.z * scale, a3 = v.w * scale;
  _Float16 h0 = (_Float16)a0, h1 = (_Float16)a1, h2 = (_Float16)a2, h3 = (_Float16)a3;
  _Float16 l0 = (_Float16)(a0 - (float)h0), l1 = (_Float16)(a1 - (float)h1);
  _Float16 l2 = (_Float16)(a2 - (float)h2), l3 = (_Float16)(a3 - (float)h3);
  union { _Float16 h; unsigned short u; } c;
  unsigned int hu0, hu1, hu2, hu3, lu0, lu1, lu2, lu3;
  c.h = h0; hu0 = c.u; c.h = h1; hu1 = c.u; c.h = h2; hu2 = c.u; c.h = h3; hu3 = c.u;
  c.h = l0; lu0 = c.u; c.h = l1; lu1 = c.u; c.h = l2; lu2 = c.u; c.h = l3; lu3 = c.u;
  uint4 r;
  r.x = hu0 | (hu1 << 16);
  r.y = hu2 | (hu3 << 16);
  r.z = lu0 | (lu1 << 16);
  r.w = lu2 | (lu3 << 16);
  return r;
}

__device__ __forceinline__ unsigned int pack2h(float a, float b) {
  union { _Float16 h; unsigned short u; } x, y;
  x.h = (_Float16)a; y.h = (_Float16)b;
  return (unsigned int)x.u | ((unsigned int)y.u << 16);
}

// ---------------- prep: W1 split (blocks 0..255) | W2 split (256..264) |
// Kp[c][h] = 256*td_p[h]*W2[v][h] AND K2p[c][h] = 65536*td_p^2*W2[v][h],
// c = p*17+v, zero-padded to 304 (blocks 265..568).
__global__ __launch_bounds__(256)
void prep_kernel(const float* __restrict__ W1, const float* __restrict__ W2,
                 const float* __restrict__ table,
                 unsigned int* __restrict__ WHI, unsigned int* __restrict__ WLO,
                 unsigned int* __restrict__ W2HI, unsigned int* __restrict__ W2LO,
                 unsigned int* __restrict__ Kp, unsigned int* __restrict__ K2p) {
  const int bid = blockIdx.x, t = threadIdx.x;
  if (bid < 256) {
    const int idx = bid * 256 + t;
    const int row = idx >> 7, c4 = idx & 127;
    const float4 wv = *(const float4*)&W1[(size_t)row * (D_ + E_) + 4 * c4];
    const uint4 pw = split4(wv, SCALE_W);
    *(uint2*)&WHI[row * 256 + 2 * c4] = make_uint2(pw.x, pw.y);
    *(uint2*)&WLO[row * 256 + 2 * c4] = make_uint2(pw.z, pw.w);
  } else if (bid < 265) {
    const int i = (bid - 256) * 256 + t;
    if (i < V_ * 128) {
      const int row = i >> 7, c4 = i & 127;
      const float4 wv = *(const float4*)&W2[(size_t)row * H_ + 4 * c4];
      const uint4 pw = split4(wv, SCALE_W);
      *(uint2*)&W2HI[row * 256 + 2 * c4] = make_uint2(pw.x, pw.y);
      *(uint2*)&W2LO[row * 256 + 2 * c4] = make_uint2(pw.z, pw.w);
    }
  } else {
    const int c = bid - 265;          // 0..303
    unsigned int o1 = 0, o2 = 0;
    if (c < 289) {
      const int p = c / 17, v = c - p * 17;
      float k1[2], k2[2];
#pragma unroll
      for (int s = 0; s < 2; ++s) {
        const int h = 2 * t + s;
        float td = 0.f;
        if (p > 0) {
          float acc = 0.f;
          for (int e = 0; e < E_; ++e)
            acc += W1[(size_t)h * (D_ + E_) + D_ + e] * table[p * E_ + e];
          td = fast_tanh(acc);
        }
        const float w2v = W2[(size_t)v * H_ + h];
        k1[s] = 256.0f * td * w2v;
        k2[s] = 65536.0f * td * td * w2v;
      }
      o1 = pack2h(k1[0], k1[1]);
      o2 = pack2h(k2[0], k2[1]);
    }
    Kp[c * 256 + t] = o1;
    K2p[c * 256 + t] = o2;
  }
}

// ---------------- split-fp16 3xMFMA GEMM, full-N blocks: TZ = tanh(A*W1^T + b1)
// (verified passing, round 5)
__global__ __launch_bounds__(512, 2)
void gemm_kernel(const float* __restrict__ A, const unsigned int* __restrict__ WHI,
                 const unsigned int* __restrict__ WLO,
                 const float* __restrict__ b1, float* __restrict__ TZ) {
  __shared__ unsigned int Ahi[128 * PITCH], Alo[128 * PITCH];
  __shared__ unsigned int Whi[512 * PITCH], Wlo[512 * PITCH];

  const int t = threadIdx.x;
  const int ln = t & 63, w = t >> 6;
  const int wm = w & 1, wn = w >> 1;
  const int mBase = blockIdx.x * 128;
  const int lrow = ln & 15, lquad = ln >> 4;

  float4v acc[4][8];
#pragma unroll
  for (int i = 0; i < 4; ++i)
#pragma unroll
    for (int j = 0; j < 8; ++j) acc[i][j] = (float4v){0.f, 0.f, 0.f, 0.f};

  for (int kt = 0; kt < D_; kt += 32) {
#pragma unroll
    for (int q = 0; q < 2; ++q) {
      const int idx = q * 512 + t;
      const int m = idx >> 3, f = idx & 7;
      const float4 av = *(const float4*)&A[(size_t)(mBase + m) * D_ + kt + 4 * f];
      const uint4 pa = split4(av, SCALE_A);
      *(uint2*)&Ahi[m * PITCH + 2 * f] = make_uint2(pa.x, pa.y);
      *(uint2*)&Alo[m * PITCH + 2 * f] = make_uint2(pa.z, pa.w);
    }
#pragma unroll
    for (int q = 0; q < 4; ++q) {
      const int idx = q * 512 + t;
      const int n = idx >> 2, d4 = (idx & 3) * 4;
      *(uint4*)&Whi[n * PITCH + d4] = *(const uint4*)&WHI[n * 256 + (kt >> 1) + d4];
      *(uint4*)&Wlo[n * PITCH + d4] = *(const uint4*)&WLO[n * 256 + (kt >> 1) + d4];
    }
    __syncthreads();

    half8 ah[4], al[4];
#pragma unroll
    for (int tm = 0; tm < 4; ++tm) {
      const int off = (wm * 64 + tm * 16 + lrow) * PITCH + 4 * lquad;
      ah[tm] = *(const half8*)&Ahi[off];
      al[tm] = *(const half8*)&Alo[off];
    }
#pragma unroll
    for (int tn = 0; tn < 8; ++tn) {
      const int off = (wn * 128 + tn * 16 + lrow) * PITCH + 4 * lquad;
      const half8 bh = *(const half8*)&Whi[off];
      const half8 bl = *(const half8*)&Wlo[off];
#pragma unroll
      for (int tm = 0; tm < 4; ++tm) {
        acc[tm][tn] = __builtin_amdgcn_mfma_f32_16x16x32_f16(ah[tm], bh, acc[tm][tn], 0, 0, 0);
        acc[tm][tn] = __builtin_amdgcn_mfma_f32_16x16x32_f16(ah[tm], bl, acc[tm][tn], 0, 0, 0);
        acc[tm][tn] = __builtin_amdgcn_mfma_f32_16x16x32_f16(al[tm], bh, acc[tm][tn], 0, 0, 0);
      }
    }
    __syncthreads();
  }

#pragma unroll
  for (int tn = 0; tn < 8; ++tn) {
    const int col = wn * 128 + tn * 16 + lrow;
    const float bv = b1[col];
#pragma unroll
    for (int tm = 0; tm < 4; ++tm) {
      const int row0 = mBase + wm * 64 + tm * 16 + lquad * 4;
#pragma unroll
      for (int r = 0; r < 4; ++r)
        TZ[(size_t)(row0 + r) * H_ + col] = fast_tanh(acc[tm][tn][r] * INV_SCALE + bv);
    }
  }
}

// ---------------- glog: G[row][p][v] = base + corr1 + corr2
//   base  = sum_h tz*W2          (3-pass split MFMA)
//   corr1 = sum_h u*td*W2        (A=u f16, B=Kp=256*td*W2 f16)
//   corr2 = -sum_h u*tz*td^2*W2  (A=-u*tz/256 f16, B=K2p=65536*td^2*W2 f16)
// corr2 folds into the SAME accumulator (epilogue x1/256 applies to both).
// Remaining error = O(td^3) ~1e-7 -- round-5 error class.
__global__ __launch_bounds__(512, 1)
void glog_kernel(const float* Zin, const unsigned int* __restrict__ KpD,
                 const unsigned int* __restrict__ K2D,
                 const unsigned int* __restrict__ W2HI, const unsigned int* __restrict__ W2LO,
                 const float* __restrict__ b2, float* G) {   // G aliases Zin
  __shared__ __align__(16) char pool[97408];
  unsigned int* Ahi = (unsigned int*)pool;   // 128*20 d
  unsigned int* Alo = Ahi + 2560;
  unsigned int* Uf  = Alo + 2560;
  unsigned int* A2f = Uf + 2560;
  unsigned int* Bc  = A2f + 2560;            // 304*20 d (Kp)
  unsigned int* Bc2 = Bc + 6080;             // 304*20 d (K2p)
  unsigned int* Bh  = Bc2 + 6080;            // 32*20 d
  unsigned int* Bl  = Bh + 640;
  // staging total 23680 dwords = 94720 B <= 97408

  const int t = threadIdx.x;
  const int ln = t & 63, w = t >> 6;
  const int wm = w & 1, wn = w >> 1;
  const int lrow = ln & 15, lq = ln >> 4;
  const int bt0 = blockIdx.x * 128;

  if (t < 300) { Bh[340 + t] = 0; Bl[340 + t] = 0; }  // pad rows 17..31 once

  float4v accC[5][4];
  float4v accB[2][4];
#pragma unroll
  for (int i = 0; i < 5; ++i)
#pragma unroll
    for (int mt = 0; mt < 4; ++mt) accC[i][mt] = (float4v){0.f, 0.f, 0.f, 0.f};
#pragma unroll
  for (int i = 0; i < 2; ++i)
#pragma unroll
    for (int mt = 0; mt < 4; ++mt) accB[i][mt] = (float4v){0.f, 0.f, 0.f, 0.f};

  for (int kt = 0; kt < H_; kt += 32) {
    // stage A: tz split (x1024), u = 1-tz^2, a2 = -u*tz/256 (f16)
#pragma unroll
    for (int i = 0; i < 2; ++i) {
      const int idx = i * 512 + t;
      const int m = idx >> 3, f = idx & 7;
      const float4 z = *(const float4*)&Zin[(size_t)(bt0 + m) * H_ + kt + 4 * f];
      const uint4 pa = split4(z, SCALE_A);
      *(uint2*)&Ahi[m * PITCH + 2 * f] = make_uint2(pa.x, pa.y);
      *(uint2*)&Alo[m * PITCH + 2 * f] = make_uint2(pa.z, pa.w);
      const float u0 = fmaf(-z.x, z.x, 1.0f), u1 = fmaf(-z.y, z.y, 1.0f);
      const float u2 = fmaf(-z.z, z.z, 1.0f), u3 = fmaf(-z.w, z.w, 1.0f);
      *(uint2*)&Uf[m * PITCH + 2 * f] = make_uint2(pack2h(u0, u1), pack2h(u2, u3));
      const float s2 = -1.0f / 256.0f;
      *(uint2*)&A2f[m * PITCH + 2 * f] =
          make_uint2(pack2h(u0 * z.x * s2, u1 * z.y * s2),
                     pack2h(u2 * z.z * s2, u3 * z.w * s2));
    }
    // stage corr B tables: Kp and K2p rows 0..303
#pragma unroll
    for (int i = 0; i < 3; ++i) {
      const int idx = i * 512 + t;
      if (idx < NC * 4) {
        const int c = idx >> 2, g4 = (idx & 3) * 4;
        *(uint4*)&Bc[c * PITCH + g4]  = *(const uint4*)&KpD[c * 256 + (kt >> 1) + g4];
        *(uint4*)&Bc2[c * PITCH + g4] = *(const uint4*)&K2D[c * 256 + (kt >> 1) + g4];
      }
    }
    // stage base B: W2 split rows 0..16
    if (t < 68) {
      const int v = t >> 2, g4 = (t & 3) * 4;
      *(uint4*)&Bh[v * PITCH + g4] = *(const uint4*)&W2HI[v * 256 + (kt >> 1) + g4];
    } else if (t < 136) {
      const int t2 = t - 68, v = t2 >> 2, g4 = (t2 & 3) * 4;
      *(uint4*)&Bl[v * PITCH + g4] = *(const uint4*)&W2LO[v * 256 + (kt >> 1) + g4];
    }
    __syncthreads();

    half8 fa_hi[4], fa_lo[4], fa_u[4], fa_a2[4];
#pragma unroll
    for (int mt = 0; mt < 4; ++mt) {
      const int off = (wm * 64 + mt * 16 + lrow) * PITCH + 4 * lq;
      fa_hi[mt] = *(const half8*)&Ahi[off];
      fa_lo[mt] = *(const half8*)&Alo[off];
      fa_u[mt]  = *(const half8*)&Uf[off];
      fa_a2[mt] = *(const half8*)&A2f[off];
    }
#pragma unroll
    for (int i = 0; i < 5; ++i) {
      if (wn < 3 || i < 4) {
        const int c = (wn * 5 + i) * 16 + lrow;
        const half8 fb  = *(const half8*)&Bc[c * PITCH + 4 * lq];
        const half8 fb2 = *(const half8*)&Bc2[c * PITCH + 4 * lq];
#pragma unroll
        for (int mt = 0; mt < 4; ++mt) {
          accC[i][mt] = __builtin_amdgcn_mfma_f32_16x16x32_f16(fa_u[mt], fb, accC[i][mt], 0, 0, 0);
          accC[i][mt] = __builtin_amdgcn_mfma_f32_16x16x32_f16(fa_a2[mt], fb2, accC[i][mt], 0, 0, 0);
        }
      }
    }
    if (wn == 3) {
#pragma unroll
      for (int bt2 = 0; bt2 < 2; ++bt2) {
        const int off = (bt2 * 16 + lrow) * PITCH + 4 * lq;
        const half8 bh = *(const half8*)&Bh[off];
        const half8 bl = *(const half8*)&Bl[off];
#pragma unroll
        for (int mt = 0; mt < 4; ++mt) {
          accB[bt2][mt] = __builtin_amdgcn_mfma_f32_16x16x32_f16(fa_hi[mt], bh, accB[bt2][mt], 0, 0, 0);
          accB[bt2][mt] = __builtin_amdgcn_mfma_f32_16x16x32_f16(fa_hi[mt], bl, accB[bt2][mt], 0, 0, 0);
          accB[bt2][mt] = __builtin_amdgcn_mfma_f32_16x16x32_f16(fa_lo[mt], bh, accB[bt2][mt], 0, 0, 0);
        }
      }
    }
    __syncthreads();
  }

  // ---- epilogue (LDS overlay; staging dead after last barrier)
  float* Gbuf = (float*)pool;                 // [64][353] f32
  float* Bb   = Gbuf + 64 * 353;              // [64][21]
  float* sb2  = Bb + 64 * 21;                 // [20]
  unsigned char* nbb = (unsigned char*)(sb2 + 20);  // [64][20]

  if (t < V_) sb2[t] = b2[t];

#pragma unroll
  for (int half = 0; half < 2; ++half) {
    if (half) __syncthreads();                 // protect half-0's Gbuf/nbb reads
    if (wm == half) {
#pragma unroll
      for (int i = 0; i < 5; ++i) {
        if (wn < 3 || i < 4) {
          const int c = (wn * 5 + i) * 16 + lrow;
          if (c < 289) {
            const int p = c / 17, v = c - p * 17;
            const int j = p * 20 + v;
#pragma unroll
            for (int mt = 0; mt < 4; ++mt)
#pragma unroll
              for (int r = 0; r < 4; ++r)
                Gbuf[(mt * 16 + lq * 4 + r) * 353 + j] = accC[i][mt][r] * (1.0f / 256.0f);
          }
        }
      }
      if (wn == 3) {
#pragma unroll
        for (int bt2 = 0; bt2 < 2; ++bt2) {
          const int v = bt2 * 16 + lrow;
          if (v < V_) {
#pragma unroll
            for (int mt = 0; mt < 4; ++mt)
#pragma unroll
              for (int r = 0; r < 4; ++r)
                Bb[(mt * 16 + lq * 4 + r) * 21 + v] = accB[bt2][mt][r] * INV_SCALE;
          }
        }
      }
    }
    __syncthreads();
    // emit: 1088 tasks = (row 0..63) x (p 0..16)
#pragma unroll
    for (int k = 0; k < 3; ++k) {
      const int task = k * 512 + t;
      if (task < 1088) {
        const int row = task & 63, p = task >> 6;
        float g[17];
#pragma unroll
        for (int v = 0; v < V_; ++v)
          g[v] = Gbuf[row * 353 + p * 20 + v] + Bb[row * 21 + v] + sb2[v];
        float m = g[0]; int am = 0;
#pragma unroll
        for (int v = 1; v < V_; ++v) if (g[v] > m) { m = g[v]; am = v; }
        float* gs = &G[(size_t)(bt0 + half * 64 + row) * H_ + p * 20];
        *(float4*)&gs[0]  = make_float4(g[0], g[1], g[2], g[3]);
        *(float4*)&gs[4]  = make_float4(g[4], g[5], g[6], g[7]);
        *(float4*)&gs[8]  = make_float4(g[8], g[9], g[10], g[11]);
        *(float4*)&gs[12] = make_float4(g[12], g[13], g[14], g[15]);
        gs[16] = g[16];
        nbb[row * 20 + p] = (unsigned char)am;
      }
    }
    __syncthreads();
    if (t < 320) {
      const int row = t / 5, d = t % 5;
      ((unsigned int*)&G[(size_t)(bt0 + half * 64 + row) * H_ + 352])[d] =
          *(const unsigned int*)&nbb[row * 20 + 4 * d];
    }
  }
}

// ---------------- chase_kernel (round-5 verified): byte-table walk.
__global__ __launch_bounds__(64, 1)
void chase_kernel(const float* __restrict__ G, float* __restrict__ out_preds) {
  __shared__ unsigned char nxt[L_ * 32];   // 16 KB
  const int b = blockIdx.x, ln = threadIdx.x;
#pragma unroll
  for (int i = 0; i < 8; ++i) {
    const int tt = ln + 64 * i;
    const unsigned int* src = (const unsigned int*)&G[((size_t)b * L_ + tt) * H_ + 352];
    *(uint4*)&nxt[tt * 32] = *(const uint4*)src;
    *(unsigned int*)&nxt[tt * 32 + 16] = src[4];
  }
  __syncthreads();
  int pred = 0;
  float* op = out_preds + (size_t)b * L_;
  for (int tt = 0; tt < L_; ++tt) {
    pred = nxt[tt * 32 + pred];
    if (ln == 0) op[tt] = (float)pred;
  }
}

// ---------------- epi_kernel (round-5 verified): outputs from G + preds.
__global__ __launch_bounds__(256)
void epi_kernel(const float* __restrict__ G, const float* __restrict__ table,
                const float* __restrict__ preds,
                float* __restrict__ out_logits, float* __restrict__ out_probs,
                float* __restrict__ out_pemb) {
  const int bt = blockIdx.x * 256 + threadIdx.x;
  const int tt = bt & (L_ - 1);
  const int p = (tt == 0) ? 0 : (int)preds[bt - 1];
  const float* g = &G[(size_t)bt * H_ + p * 20];
  float va[17];
  {
    const float4 q0 = *(const float4*)&g[0];
    const float4 q1 = *(const float4*)&g[4];
    const float4 q2 = *(const float4*)&g[8];
    const float4 q3 = *(const float4*)&g[12];
    va[0] = q0.x; va[1] = q0.y; va[2] = q0.z; va[3] = q0.w;
    va[4] = q1.x; va[5] = q1.y; va[6] = q1.z; va[7] = q1.w;
    va[8] = q2.x; va[9] = q2.y; va[10] = q2.z; va[11] = q2.w;
    va[12] = q3.x; va[13] = q3.y; va[14] = q3.z; va[15] = q3.w;
    va[16] = g[16];
  }
  float m = va[0];
#pragma unroll
  for (int i = 1; i < V_; ++i) m = fmaxf(m, va[i]);
  float s = 0.f;
#pragma unroll
  for (int i = 0; i < V_; ++i) s += __builtin_amdgcn_exp2f((va[i] - m) * LOG2E_F);
  const float lse = __builtin_amdgcn_logf(s) * LN2_F;
  float* lo = out_logits + (size_t)bt * V_;
  float* pb = out_probs + (size_t)bt * V_;
#pragma unroll
  for (int i = 0; i < V_; ++i) { lo[i] = va[i]; pb[i] = va[i] - m - lse; }
  const int pr = (int)preds[bt];
  float* pe = out_pemb + (size_t)bt * E_;
  if (pr == 0) {
#pragma unroll
    for (int i = 0; i < 16; ++i) *(float4*)&pe[4 * i] = (float4){0.f, 0.f, 0.f, 0.f};
  } else {
    const float* tr = &table[(size_t)pr * E_];
#pragma unroll
    for (int i = 0; i < 16; ++i) *(float4*)&pe[4 * i] = *(const float4*)&tr[4 * i];
  }
}

extern "C" void kernel_launch(void* const* d_in, const int* in_sizes, int n_in,
                              void* d_out, int out_size, void* d_ws, size_t ws_size,
                              hipStream_t stream) {
  const float* inputs = (const float*)d_in[0];
  const float* table  = (const float*)d_in[1];
  const float* W1     = (const float*)d_in[2];
  const float* b1     = (const float*)d_in[3];
  const float* W2     = (const float*)d_in[4];
  const float* b2     = (const float*)d_in[5];

  float* out = (float*)d_out;
  float* out_logits = out;                                  // [B,L,V]
  float* out_preds  = out_logits + (size_t)B_ * L_ * V_;    // [B,L]
  float* out_probs  = out_preds + (size_t)B_ * L_;          // [B,L,V]
  float* out_pemb   = out_probs + (size_t)B_ * L_ * V_;     // [B,L,E]

  // d_ws: [0,64K) = W2 splits; [64K, +128MB) = TZ (becomes G in place)
  unsigned int* W2HI = (unsigned int*)d_ws;                 // 17*256 dwords
  unsigned int* W2LO = W2HI + V_ * 256;                     // total 34,816 B < 64K
  float* TZ = (float*)((char*)d_ws + 65536);

  // scratch carved from outputs (consumed before the final kernels rewrite them)
  unsigned int* WHI = (unsigned int*)out_pemb;              // 512 KB
  unsigned int* WLO = WHI + 512 * 256;                      // 512 KB (total 1 MB < 16.8 MB)
  unsigned int* Kp  = (unsigned int*)out_probs;             // 311 KB
  unsigned int* K2p = Kp + NC * 256;                        // 311 KB (total < 4.25 MB)

  prep_kernel<<<569, 256, 0, stream>>>(W1, W2, table, WHI, WLO, W2HI, W2LO, Kp, K2p);
  gemm_kernel<<<512, 512, 0, stream>>>(inputs, WHI, WLO, b1, TZ);
  glog_kernel<<<512, 512, 0, stream>>>(TZ, Kp, K2p, W2HI, W2LO, b2, TZ);
  chase_kernel<<<B_, 64, 0, stream>>>(TZ, out_preds);
  epi_kernel<<<65536 / 256, 256, 0, stream>>>(TZ, table, out_preds,
                                              out_logits, out_probs, out_pemb);
}